// Round 1
// baseline (158.535 us; speedup 1.0000x reference)
//
#include <hip/hip_runtime.h>
#include <math.h>

// Problem shape (fixed by the reference)
constexpr int Bn = 512;   // batch
constexpr int Tn = 77;    // text tokens
constexpr int Fn = 12;    // video frames
constexpr int Dn = 512;   // feature dim

// ---------------- DPP wave-wide reductions (pure VALU, no LDS pipe) -------
// Result valid in lane 63 only. Sequence: quad xor1, xor2, half-mirror,
// mirror (=> per-16-row total in all row lanes), then bcast15 (rows 1,3),
// bcast31 (rows 2,3) => full-wave total in lanes 48..63.

template <int ctrl, int rm>
__device__ __forceinline__ float dpp_add_step(float x) {
  int y = __builtin_amdgcn_update_dpp(0, __float_as_int(x), ctrl, rm, 0xF, true);
  return x + __int_as_float(y);
}

__device__ __forceinline__ float wave_sum63(float x) {
  x = dpp_add_step<0xB1, 0xF>(x);   // quad_perm [1,0,3,2]  (xor 1)
  x = dpp_add_step<0x4E, 0xF>(x);   // quad_perm [2,3,0,1]  (xor 2)
  x = dpp_add_step<0x141, 0xF>(x);  // row_half_mirror      (xor 4 equiv)
  x = dpp_add_step<0x140, 0xF>(x);  // row_mirror           (xor 8 equiv)
  x = dpp_add_step<0x142, 0xA>(x);  // row_bcast15 -> rows 1,3
  x = dpp_add_step<0x143, 0xC>(x);  // row_bcast31 -> rows 2,3
  return x;                         // lane 63 = total
}

template <int ctrl, int rm>
__device__ __forceinline__ float dpp_min_step(float x) {
  // old = x so masked/invalid lanes do min(x, x) = x (identity)
  int y = __builtin_amdgcn_update_dpp(__float_as_int(x), __float_as_int(x),
                                      ctrl, rm, 0xF, false);
  return fminf(x, __int_as_float(y));
}
template <int ctrl, int rm>
__device__ __forceinline__ float dpp_max_step(float x) {
  int y = __builtin_amdgcn_update_dpp(__float_as_int(x), __float_as_int(x),
                                      ctrl, rm, 0xF, false);
  return fmaxf(x, __int_as_float(y));
}

__device__ __forceinline__ float wave_min63(float x) {
  x = dpp_min_step<0xB1, 0xF>(x);
  x = dpp_min_step<0x4E, 0xF>(x);
  x = dpp_min_step<0x141, 0xF>(x);
  x = dpp_min_step<0x140, 0xF>(x);
  x = dpp_min_step<0x142, 0xA>(x);
  x = dpp_min_step<0x143, 0xC>(x);
  return x;
}
__device__ __forceinline__ float wave_max63(float x) {
  x = dpp_max_step<0xB1, 0xF>(x);
  x = dpp_max_step<0x4E, 0xF>(x);
  x = dpp_max_step<0x141, 0xF>(x);
  x = dpp_max_step<0x140, 0xF>(x);
  x = dpp_max_step<0x142, 0xA>(x);
  x = dpp_max_step<0x143, 0xC>(x);
  return x;
}

__device__ __forceinline__ float dot8(const float4& a0, const float4& a1,
                                      const float4& b0, const float4& b1) {
  return a0.x * b0.x + a0.y * b0.y + a0.z * b0.z + a0.w * b0.w +
         a1.x * b1.x + a1.y * b1.y + a1.z * b1.z + a1.w * b1.w;
}

// -------------------- Kernel A: per-(b,half) dmin/dmax ---------------------
// grid = 1024 blocks (2 per batch, t-ranges [0,40) and [40,77)), 256 threads.
// Each wave holds the full normalized 12x512 video tile of its batch in
// registers (lanes split K: lane owns elems [4*lane,4*lane+4) and
// [256+4*lane, ...)) and streams text rows with depth-1 prefetch.
__global__ void minmax_kernel(const float* __restrict__ text,
                              const float* __restrict__ video,
                              float* __restrict__ dminh,
                              float* __restrict__ dmaxh) {
  const int b    = blockIdx.x >> 1;
  const int half = blockIdx.x & 1;
  const int wave = threadIdx.x >> 6;
  const int lane = threadIdx.x & 63;

  // ---- load video fragments (coalesced float4) and normalize in-register
  const float4* vbase = (const float4*)(video + (size_t)b * Fn * Dn);
  float4 vf[Fn][2];
#pragma unroll
  for (int f = 0; f < Fn; ++f) {
    vf[f][0] = vbase[f * 128 + lane];
    vf[f][1] = vbase[f * 128 + 64 + lane];
  }
#pragma unroll
  for (int f = 0; f < Fn; ++f) {
    float s = dot8(vf[f][0], vf[f][1], vf[f][0], vf[f][1]);
    s = wave_sum63(s);
    // broadcast lane 63's sum to all lanes, scale fragment by 1/||v||
    float inv = __int_as_float(__builtin_amdgcn_readlane(__float_as_int(s), 63));
    inv = 1.0f / sqrtf(inv);
    vf[f][0].x *= inv; vf[f][0].y *= inv; vf[f][0].z *= inv; vf[f][0].w *= inv;
    vf[f][1].x *= inv; vf[f][1].y *= inv; vf[f][1].z *= inv; vf[f][1].w *= inv;
  }

  // ---- stream text rows of this half, one wave per t (stride 4)
  const float4* tbase = (const float4*)(text + (size_t)b * Tn * Dn);
  const int tend = half ? Tn : 40;
  int t = (half ? 40 : 0) + wave;

  float wmin = 1e30f, wmax = -1e30f;  // valid on lane 63 only

  float4 ta0 = make_float4(0, 0, 0, 0), ta1 = ta0;
  if (t < tend) { ta0 = tbase[t * 128 + lane]; ta1 = tbase[t * 128 + 64 + lane]; }

  while (t < tend) {
    const int tn = t + 4;
    float4 na0 = make_float4(0, 0, 0, 0), na1 = na0;
    if (tn < tend) { na0 = tbase[tn * 128 + lane]; na1 = tbase[tn * 128 + 64 + lane]; }

    float pn = dot8(ta0, ta1, ta0, ta1);  // ||t||^2 partial
    float pd[Fn];
#pragma unroll
    for (int f = 0; f < Fn; ++f) pd[f] = dot8(ta0, ta1, vf[f][0], vf[f][1]);

    pn = wave_sum63(pn);
#pragma unroll
    for (int f = 0; f < Fn; ++f) pd[f] = wave_sum63(pd[f]);

    // epilogue: meaningful on lane 63 only (other lanes compute garbage)
    float invt = 1.0f / sqrtf(pn);
    float tmin = 1e30f, tmax = -1e30f;
#pragma unroll
    for (int f = 0; f < Fn; ++f) {
      float d = 1.0f - pd[f] * invt;
      tmin = fminf(tmin, d);
      tmax = fmaxf(tmax, d);
    }
    wmin = fminf(wmin, tmin);
    wmax = fmaxf(wmax, tmax);

    ta0 = na0; ta1 = na1;
    t = tn;
  }

  __shared__ float smin[4], smax[4];
  if (lane == 63) { smin[wave] = wmin; smax[wave] = wmax; }
  __syncthreads();
  if (threadIdx.x == 0) {
    float mn = fminf(fminf(smin[0], smin[1]), fminf(smin[2], smin[3]));
    float mx = fmaxf(fmaxf(smax[0], smax[1]), fmaxf(smax[2], smax[3]));
    dminh[blockIdx.x] = mn;
    dmaxh[blockIdx.x] = mx;
  }
}

// ------------- Kernel B1: global scalars mn, 1/(mx-mn) ---------------------
__global__ void scalars_kernel(const float* __restrict__ dminh,
                               const float* __restrict__ dmaxh,
                               float* __restrict__ sc) {
  const int lane = threadIdx.x;  // 64 threads
  float mn = 1e30f, mx = -1e30f;
  for (int i = lane; i < 2 * Bn; i += 64) {
    mn = fminf(mn, dminh[i]);
    mx = fmaxf(mx, dmaxh[i]);
  }
  mn = wave_min63(mn);
  mx = wave_max63(mx);
  if (lane == 63) {
    sc[0] = mn;
    sc[1] = 1.0f / (mx - mn);
  }
}

// ------------- Kernel B2: write the 512x512 normalized output --------------
__global__ void write_kernel(const float* __restrict__ dminh,
                             const float* __restrict__ dmaxh,
                             const float* __restrict__ sc,
                             float* __restrict__ out) {
  const float mn = sc[0], inv = sc[1];
  const int idx = blockIdx.x * 256 + threadIdx.x;  // one float4 per thread
  const int i  = idx >> 7;          // row
  const int j0 = (idx & 127) * 4;   // first col of this float4
  const float lo = (fminf(dminh[2 * i], dminh[2 * i + 1]) - mn) * inv;
  const float hi = (fmaxf(dmaxh[2 * i], dmaxh[2 * i + 1]) - mn) * inv;
  float4 v = make_float4(hi, hi, hi, hi);
  if (i >= j0 && i < j0 + 4) (&v.x)[i - j0] = lo;  // diagonal element
  ((float4*)out)[idx] = v;
}

extern "C" void kernel_launch(void* const* d_in, const int* in_sizes, int n_in,
                              void* d_out, int out_size, void* d_ws, size_t ws_size,
                              hipStream_t stream) {
  const float* text  = (const float*)d_in[0];   // [512,77,512] f32
  const float* video = (const float*)d_in[1];   // [512,12,512] f32
  float* out = (float*)d_out;                   // [512,512] f32
  float* ws  = (float*)d_ws;
  float* dminh = ws;              // [1024]
  float* dmaxh = ws + 1024;       // [1024]
  float* sc    = ws + 2048;       // [2]

  minmax_kernel<<<2 * Bn, 256, 0, stream>>>(text, video, dminh, dmaxh);
  scalars_kernel<<<1, 64, 0, stream>>>(dminh, dmaxh, sc);
  write_kernel<<<(Bn * Bn / 4) / 256, 256, 0, stream>>>(dminh, dmaxh, sc, out);
}

// Round 2
// 135.883 us; speedup vs baseline: 1.1667x; 1.1667x over previous
//
#include <hip/hip_runtime.h>
#include <math.h>

// Problem shape (fixed by the reference)
constexpr int Bn = 512;   // batch
constexpr int Tn = 77;    // text tokens
constexpr int Fn = 12;    // video frames
constexpr int Dn = 512;   // feature dim

// ---------------- DPP wave-wide reductions (pure VALU, no LDS pipe) -------
// Sum result valid in lane 63. Sequence: quad xor1, xor2, row_half_mirror,
// row_mirror (=> per-16-lane total in all row lanes), then bcast15 (rows 1,3),
// bcast31 (rows 2,3) => full-wave total in lanes 48..63.

template <int ctrl, int rm>
__device__ __forceinline__ float dpp_add_step(float x) {
  int y = __builtin_amdgcn_update_dpp(0, __float_as_int(x), ctrl, rm, 0xF, true);
  return x + __int_as_float(y);
}

__device__ __forceinline__ float wave_sum63(float x) {
  x = dpp_add_step<0xB1, 0xF>(x);   // quad_perm [1,0,3,2]  (xor 1)
  x = dpp_add_step<0x4E, 0xF>(x);   // quad_perm [2,3,0,1]  (xor 2)
  x = dpp_add_step<0x141, 0xF>(x);  // row_half_mirror
  x = dpp_add_step<0x140, 0xF>(x);  // row_mirror -> per-16 totals
  x = dpp_add_step<0x142, 0xA>(x);  // row_bcast15 -> rows 1,3
  x = dpp_add_step<0x143, 0xC>(x);  // row_bcast31 -> rows 2,3
  return x;                         // lane 63 = total
}

template <int ctrl, int rm>
__device__ __forceinline__ float dpp_min_step(float x) {
  // old = x so masked/invalid lanes contribute min(x,x) = x (identity)
  int y = __builtin_amdgcn_update_dpp(__float_as_int(x), __float_as_int(x),
                                      ctrl, rm, 0xF, false);
  return fminf(x, __int_as_float(y));
}
template <int ctrl, int rm>
__device__ __forceinline__ float dpp_max_step(float x) {
  int y = __builtin_amdgcn_update_dpp(__float_as_int(x), __float_as_int(x),
                                      ctrl, rm, 0xF, false);
  return fmaxf(x, __int_as_float(y));
}

__device__ __forceinline__ float wave_min63(float x) {
  x = dpp_min_step<0xB1, 0xF>(x);
  x = dpp_min_step<0x4E, 0xF>(x);
  x = dpp_min_step<0x141, 0xF>(x);
  x = dpp_min_step<0x140, 0xF>(x);
  x = dpp_min_step<0x142, 0xA>(x);
  x = dpp_min_step<0x143, 0xC>(x);
  return x;
}
__device__ __forceinline__ float wave_max63(float x) {
  x = dpp_max_step<0xB1, 0xF>(x);
  x = dpp_max_step<0x4E, 0xF>(x);
  x = dpp_max_step<0x141, 0xF>(x);
  x = dpp_max_step<0x140, 0xF>(x);
  x = dpp_max_step<0x142, 0xA>(x);
  x = dpp_max_step<0x143, 0xC>(x);
  return x;
}

__device__ __forceinline__ float dot8(const float4& a0, const float4& a1,
                                      const float4& b0, const float4& b1) {
  return a0.x * b0.x + a0.y * b0.y + a0.z * b0.z + a0.w * b0.w +
         a1.x * b1.x + a1.y * b1.y + a1.z * b1.z + a1.w * b1.w;
}

// -------------------- Kernel A: per-batch dmin/dmax ------------------------
// grid = 512 blocks (1 per batch), 256 threads = 4 waves. Each wave holds the
// full normalized 12x512 video tile of its batch in registers (lanes split K:
// lane owns elems [4*lane,4*lane+4) and [256+4*lane,...)) and streams text
// rows t = wave, wave+4, ... with depth-1 prefetch.
// __launch_bounds__(256,2): 2 waves/SIMD -> <=256 VGPR, no spill, 8 waves/CU.
__global__ __launch_bounds__(256, 2) void
minmax_kernel(const float* __restrict__ text,
              const float* __restrict__ video,
              float* __restrict__ dminb,
              float* __restrict__ dmaxb) {
  const int b    = blockIdx.x;
  const int wave = threadIdx.x >> 6;
  const int lane = threadIdx.x & 63;

  // ---- load video fragments (coalesced float4) and normalize in-register
  const float4* vbase = (const float4*)(video + (size_t)b * Fn * Dn);
  float4 vf[Fn][2];
#pragma unroll
  for (int f = 0; f < Fn; ++f) {
    vf[f][0] = vbase[f * 128 + lane];
    vf[f][1] = vbase[f * 128 + 64 + lane];
  }
#pragma unroll
  for (int f = 0; f < Fn; ++f) {
    float s = dot8(vf[f][0], vf[f][1], vf[f][0], vf[f][1]);
    s = wave_sum63(s);
    float inv = __int_as_float(__builtin_amdgcn_readlane(__float_as_int(s), 63));
    inv = 1.0f / sqrtf(inv);
    vf[f][0].x *= inv; vf[f][0].y *= inv; vf[f][0].z *= inv; vf[f][0].w *= inv;
    vf[f][1].x *= inv; vf[f][1].y *= inv; vf[f][1].z *= inv; vf[f][1].w *= inv;
  }

  // ---- stream text rows, one wave per t (stride 4), depth-1 prefetch
  const float4* tbase = (const float4*)(text + (size_t)b * Tn * Dn);
  int t = wave;  // always < 77

  float wmin = 1e30f, wmax = -1e30f;  // valid on lane 63 only

  float4 ta0 = tbase[t * 128 + lane];
  float4 ta1 = tbase[t * 128 + 64 + lane];

  while (t < Tn) {
    const int tn = t + 4;
    float4 na0 = make_float4(0, 0, 0, 0), na1 = na0;
    if (tn < Tn) { na0 = tbase[tn * 128 + lane]; na1 = tbase[tn * 128 + 64 + lane]; }

    float pn = dot8(ta0, ta1, ta0, ta1);  // ||t||^2 partial
    float pd[Fn];
#pragma unroll
    for (int f = 0; f < Fn; ++f) pd[f] = dot8(ta0, ta1, vf[f][0], vf[f][1]);

    pn = wave_sum63(pn);
#pragma unroll
    for (int f = 0; f < Fn; ++f) pd[f] = wave_sum63(pd[f]);

    // epilogue: meaningful on lane 63 only (other lanes compute garbage)
    float invt = 1.0f / sqrtf(pn);
    float tmin = 1e30f, tmax = -1e30f;
#pragma unroll
    for (int f = 0; f < Fn; ++f) {
      float d = 1.0f - pd[f] * invt;
      tmin = fminf(tmin, d);
      tmax = fmaxf(tmax, d);
    }
    wmin = fminf(wmin, tmin);
    wmax = fmaxf(wmax, tmax);

    ta0 = na0; ta1 = na1;
    t = tn;
  }

  __shared__ float smin[4], smax[4];
  if (lane == 63) { smin[wave] = wmin; smax[wave] = wmax; }
  __syncthreads();
  if (threadIdx.x == 0) {
    float mn = fminf(fminf(smin[0], smin[1]), fminf(smin[2], smin[3]));
    float mx = fmaxf(fmaxf(smax[0], smax[1]), fmaxf(smax[2], smax[3]));
    dminb[b] = mn;
    dmaxb[b] = mx;
  }
}

// ---- Kernel B: fused global-scalar reduction + 512x512 output write -------
// 512 blocks (1 per output row) x 256 threads. Each block redundantly
// reduces the 512-entry dminb/dmaxb arrays (L2-resident, 2 MB total L2 reads
// across all blocks) and writes its row with float2 stores.
__global__ __launch_bounds__(256) void
out_kernel(const float* __restrict__ dminb,
           const float* __restrict__ dmaxb,
           float* __restrict__ out) {
  const int b    = blockIdx.x;
  const int tid  = threadIdx.x;
  const int wave = tid >> 6;
  const int lane = tid & 63;

  float mn = fminf(dminb[tid], dminb[tid + 256]);
  float mx = fmaxf(dmaxb[tid], dmaxb[tid + 256]);
  mn = wave_min63(mn);
  mx = wave_max63(mx);

  __shared__ float smin[4], smax[4];
  if (lane == 63) { smin[wave] = mn; smax[wave] = mx; }
  __syncthreads();
  mn = fminf(fminf(smin[0], smin[1]), fminf(smin[2], smin[3]));
  mx = fmaxf(fmaxf(smax[0], smax[1]), fmaxf(smax[2], smax[3]));

  const float inv = 1.0f / (mx - mn);
  const float lo  = (dminb[b] - mn) * inv;   // diagonal value of row b
  const float hi  = (dmaxb[b] - mn) * inv;   // off-diagonal value of row b

  const int c = tid * 2;
  float2 v = make_float2(hi, hi);
  if (c == b)     v.x = lo;
  if (c + 1 == b) v.y = lo;
  ((float2*)(out + (size_t)b * Bn))[tid] = v;
}

extern "C" void kernel_launch(void* const* d_in, const int* in_sizes, int n_in,
                              void* d_out, int out_size, void* d_ws, size_t ws_size,
                              hipStream_t stream) {
  const float* text  = (const float*)d_in[0];   // [512,77,512] f32
  const float* video = (const float*)d_in[1];   // [512,12,512] f32
  float* out = (float*)d_out;                   // [512,512] f32
  float* ws  = (float*)d_ws;
  float* dminb = ws;          // [512]
  float* dmaxb = ws + 512;    // [512]

  minmax_kernel<<<Bn, 256, 0, stream>>>(text, video, dminb, dmaxb);
  out_kernel<<<Bn, 256, 0, stream>>>(dminb, dmaxb, out);
}

// Round 3
// 135.765 us; speedup vs baseline: 1.1677x; 1.0009x over previous
//
#include <hip/hip_runtime.h>
#include <math.h>

// Problem shape (fixed by the reference)
constexpr int Bn = 512;   // batch
constexpr int Tn = 77;    // text tokens
constexpr int Fn = 12;    // video frames
constexpr int Dn = 512;   // feature dim

typedef float v2f __attribute__((ext_vector_type(2)));

// packed fp32 FMA (gfx90a+): acc = a*b + acc, two lanes of fp32 per op
__device__ __forceinline__ void pk_fma(v2f& acc, v2f a, v2f b) {
  asm("v_pk_fma_f32 %0, %1, %2, %0" : "+v"(acc) : "v"(a), "v"(b));
}

// ---------------- DPP wave-wide reductions (pure VALU, no LDS pipe) -------
// Sum result valid in lane 63. quad xor1, xor2, row_half_mirror, row_mirror
// (=> per-16-lane totals), row_bcast15 (rows 1,3), row_bcast31 (rows 2,3).

template <int ctrl, int rm>
__device__ __forceinline__ float dpp_add_step(float x) {
  int y = __builtin_amdgcn_update_dpp(0, __float_as_int(x), ctrl, rm, 0xF, true);
  return x + __int_as_float(y);
}

__device__ __forceinline__ float wave_sum63(float x) {
  x = dpp_add_step<0xB1, 0xF>(x);   // quad_perm [1,0,3,2]
  x = dpp_add_step<0x4E, 0xF>(x);   // quad_perm [2,3,0,1]
  x = dpp_add_step<0x141, 0xF>(x);  // row_half_mirror
  x = dpp_add_step<0x140, 0xF>(x);  // row_mirror -> per-16 totals
  x = dpp_add_step<0x142, 0xA>(x);  // row_bcast15 -> rows 1,3
  x = dpp_add_step<0x143, 0xC>(x);  // row_bcast31 -> rows 2,3
  return x;                         // lane 63 = total
}

template <int ctrl, int rm>
__device__ __forceinline__ float dpp_min_step(float x) {
  int y = __builtin_amdgcn_update_dpp(__float_as_int(x), __float_as_int(x),
                                      ctrl, rm, 0xF, false);
  return fminf(x, __int_as_float(y));
}
template <int ctrl, int rm>
__device__ __forceinline__ float dpp_max_step(float x) {
  int y = __builtin_amdgcn_update_dpp(__float_as_int(x), __float_as_int(x),
                                      ctrl, rm, 0xF, false);
  return fmaxf(x, __int_as_float(y));
}

__device__ __forceinline__ float wave_min63(float x) {
  x = dpp_min_step<0xB1, 0xF>(x);
  x = dpp_min_step<0x4E, 0xF>(x);
  x = dpp_min_step<0x141, 0xF>(x);
  x = dpp_min_step<0x140, 0xF>(x);
  x = dpp_min_step<0x142, 0xA>(x);
  x = dpp_min_step<0x143, 0xC>(x);
  return x;
}
__device__ __forceinline__ float wave_max63(float x) {
  x = dpp_max_step<0xB1, 0xF>(x);
  x = dpp_max_step<0x4E, 0xF>(x);
  x = dpp_max_step<0x141, 0xF>(x);
  x = dpp_max_step<0x140, 0xF>(x);
  x = dpp_max_step<0x142, 0xA>(x);
  x = dpp_max_step<0x143, 0xC>(x);
  return x;
}

// 8-element partial dot via 4 packed-fp32 FMAs + 1 add
__device__ __forceinline__ float dot8(const float4& a0, const float4& a1,
                                      const float4& b0, const float4& b1) {
  v2f acc = (v2f){0.0f, 0.0f};
  pk_fma(acc, (v2f){a0.x, a0.y}, (v2f){b0.x, b0.y});
  pk_fma(acc, (v2f){a0.z, a0.w}, (v2f){b0.z, b0.w});
  pk_fma(acc, (v2f){a1.x, a1.y}, (v2f){b1.x, b1.y});
  pk_fma(acc, (v2f){a1.z, a1.w}, (v2f){b1.z, b1.w});
  return acc.x + acc.y;
}

// -------------------- Kernel A: per-batch dmin/dmax ------------------------
// 512 blocks (1/batch) x 256 threads (4 waves). Each wave holds the full
// normalized 12x512 video tile in registers (lanes split K) and streams text
// rows t = wave, wave+4, ... with depth-2 prefetch (8 KB/wave in flight).
__global__ __launch_bounds__(256, 2) void
minmax_kernel(const float* __restrict__ text,
              const float* __restrict__ video,
              float* __restrict__ dminb,
              float* __restrict__ dmaxb) {
  const int b    = blockIdx.x;
  const int wave = threadIdx.x >> 6;
  const int lane = threadIdx.x & 63;

  // ---- load video fragments (coalesced float4) and normalize in-register
  const float4* vbase = (const float4*)(video + (size_t)b * Fn * Dn);
  float4 vf[Fn][2];
#pragma unroll
  for (int f = 0; f < Fn; ++f) {
    vf[f][0] = vbase[f * 128 + lane];
    vf[f][1] = vbase[f * 128 + 64 + lane];
  }
#pragma unroll
  for (int f = 0; f < Fn; ++f) {
    float s = dot8(vf[f][0], vf[f][1], vf[f][0], vf[f][1]);
    s = wave_sum63(s);
    float inv = __int_as_float(__builtin_amdgcn_readlane(__float_as_int(s), 63));
    inv = rsqrtf(inv);
    vf[f][0].x *= inv; vf[f][0].y *= inv; vf[f][0].z *= inv; vf[f][0].w *= inv;
    vf[f][1].x *= inv; vf[f][1].y *= inv; vf[f][1].z *= inv; vf[f][1].w *= inv;
  }

  // ---- stream text rows, one wave per t (stride 4), depth-2 prefetch
  const float4* tbase = (const float4*)(text + (size_t)b * Tn * Dn);
  int t = wave;  // < 77 always

  float wmin = 1e30f, wmax = -1e30f;  // valid on lane 63 only

  float4 c0 = tbase[t * 128 + lane];
  float4 c1 = tbase[t * 128 + 64 + lane];
  float4 p0 = make_float4(0, 0, 0, 0), p1 = p0;
  if (t + 4 < Tn) { p0 = tbase[(t + 4) * 128 + lane]; p1 = tbase[(t + 4) * 128 + 64 + lane]; }

  while (t < Tn) {
    const int t2 = t + 8;
    float4 q0 = make_float4(0, 0, 0, 0), q1 = q0;
    if (t2 < Tn) { q0 = tbase[t2 * 128 + lane]; q1 = tbase[t2 * 128 + 64 + lane]; }

    float pn = dot8(c0, c1, c0, c1);  // ||t||^2 partial
    float pd[Fn];
#pragma unroll
    for (int f = 0; f < Fn; ++f) pd[f] = dot8(c0, c1, vf[f][0], vf[f][1]);

    pn = wave_sum63(pn);
#pragma unroll
    for (int f = 0; f < Fn; ++f) pd[f] = wave_sum63(pd[f]);

    // epilogue: meaningful on lane 63 only (other lanes compute garbage)
    float invt = rsqrtf(pn);
    float tmin = 1e30f, tmax = -1e30f;
#pragma unroll
    for (int f = 0; f < Fn; ++f) {
      float d = 1.0f - pd[f] * invt;
      tmin = fminf(tmin, d);
      tmax = fmaxf(tmax, d);
    }
    wmin = fminf(wmin, tmin);
    wmax = fmaxf(wmax, tmax);

    c0 = p0; c1 = p1; p0 = q0; p1 = q1;
    t += 4;
  }

  __shared__ float smin[4], smax[4];
  if (lane == 63) { smin[wave] = wmin; smax[wave] = wmax; }
  __syncthreads();
  if (threadIdx.x == 0) {
    float mn = fminf(fminf(smin[0], smin[1]), fminf(smin[2], smin[3]));
    float mx = fmaxf(fmaxf(smax[0], smax[1]), fmaxf(smax[2], smax[3]));
    dminb[b] = mn;
    dmaxb[b] = mx;
  }
}

// ---- Kernel B: fused global-scalar reduction + 512x512 output write -------
// 512 blocks (1 per output row) x 256 threads. Each block redundantly
// reduces the 512-entry dminb/dmaxb arrays (L2-resident) and writes its row.
__global__ __launch_bounds__(256) void
out_kernel(const float* __restrict__ dminb,
           const float* __restrict__ dmaxb,
           float* __restrict__ out) {
  const int b    = blockIdx.x;
  const int tid  = threadIdx.x;
  const int wave = tid >> 6;
  const int lane = tid & 63;

  float mn = fminf(dminb[tid], dminb[tid + 256]);
  float mx = fmaxf(dmaxb[tid], dmaxb[tid + 256]);
  mn = wave_min63(mn);
  mx = wave_max63(mx);

  __shared__ float smin[4], smax[4];
  if (lane == 63) { smin[wave] = mn; smax[wave] = mx; }
  __syncthreads();
  mn = fminf(fminf(smin[0], smin[1]), fminf(smin[2], smin[3]));
  mx = fmaxf(fmaxf(smax[0], smax[1]), fmaxf(smax[2], smax[3]));

  const float inv = 1.0f / (mx - mn);
  const float lo  = (dminb[b] - mn) * inv;   // diagonal value of row b
  const float hi  = (dmaxb[b] - mn) * inv;   // off-diagonal value of row b

  const int c = tid * 2;
  float2 v = make_float2(hi, hi);
  if (c == b)     v.x = lo;
  if (c + 1 == b) v.y = lo;
  ((float2*)(out + (size_t)b * Bn))[tid] = v;
}

extern "C" void kernel_launch(void* const* d_in, const int* in_sizes, int n_in,
                              void* d_out, int out_size, void* d_ws, size_t ws_size,
                              hipStream_t stream) {
  const float* text  = (const float*)d_in[0];   // [512,77,512] f32
  const float* video = (const float*)d_in[1];   // [512,12,512] f32
  float* out = (float*)d_out;                   // [512,512] f32
  float* ws  = (float*)d_ws;
  float* dminb = ws;          // [512]
  float* dmaxb = ws + 512;    // [512]

  minmax_kernel<<<Bn, 256, 0, stream>>>(text, video, dminb, dmaxb);
  out_kernel<<<Bn, 256, 0, stream>>>(dminb, dmaxb, out);
}